// Round 1
// baseline (1333.636 us; speedup 1.0000x reference)
//
#include <hip/hip_runtime.h>
#include <math.h>

#define D_MODEL 1024
#define D_STATE 128
#define SEQ_LEN 4096
#define BATCH 4
#define NTOK (BATCH * SEQ_LEN)      // 16384
#define LN_EPS 1e-3f
#define NCHUNK 64
#define LCHUNK (SEQ_LEN / NCHUNK)   // 64

// ---------------- LayerNorm: one block per token row of 1024 ----------------
__global__ __launch_bounds__(256) void ln_kernel(const float* __restrict__ x,
                                                 const float* __restrict__ gamma,
                                                 const float* __restrict__ beta,
                                                 float* __restrict__ xn) {
    int row = blockIdx.x;
    const float4* xr = (const float4*)(x + (size_t)row * D_MODEL);
    float4 v = xr[threadIdx.x];
    float s1 = v.x + v.y + v.z + v.w;
    float s2 = v.x * v.x + v.y * v.y + v.z * v.z + v.w * v.w;
    for (int off = 32; off; off >>= 1) {
        s1 += __shfl_down(s1, off);
        s2 += __shfl_down(s2, off);
    }
    __shared__ float ls1[4], ls2[4];
    int wid = threadIdx.x >> 6, lane = threadIdx.x & 63;
    if (lane == 0) { ls1[wid] = s1; ls2[wid] = s2; }
    __syncthreads();
    s1 = ls1[0] + ls1[1] + ls1[2] + ls1[3];
    s2 = ls2[0] + ls2[1] + ls2[2] + ls2[3];
    float mu = s1 * (1.0f / D_MODEL);
    float var = s2 * (1.0f / D_MODEL) - mu * mu;
    float r = rsqrtf(var + LN_EPS);
    float4 g = ((const float4*)gamma)[threadIdx.x];
    float4 b = ((const float4*)beta)[threadIdx.x];
    float4 o;
    o.x = (v.x - mu) * r * g.x + b.x;
    o.y = (v.y - mu) * r * g.y + b.y;
    o.z = (v.z - mu) * r * g.z + b.z;
    o.w = (v.w - mu) * r * g.w + b.w;
    ((float4*)(xn + (size_t)row * D_MODEL))[threadIdx.x] = o;
}

// ---------------- Generic fp32 tiled GEMM ----------------
// C[M,N] = A[M,K] @ B[K,N] (+ bias[n]) (+ addscale[n]*addmat[m,n])
// segmented: B/bias chosen per 128-column segment (for fused xs/B/C projection)
#define BM 64
#define BN 64
#define BK 16

__global__ __launch_bounds__(256) void gemm_kernel(
    const float* __restrict__ A,
    const float* __restrict__ B0, const float* __restrict__ B1, const float* __restrict__ B2,
    const float* __restrict__ bias0, const float* __restrict__ bias1, const float* __restrict__ bias2,
    const float* __restrict__ addmat, const float* __restrict__ addscale,
    float* __restrict__ C, int M, int N, int K, int segmented) {
    __shared__ float As[BK][BM + 4];   // +4 keeps rows 16B-aligned for b128 reads
    __shared__ float Bs[BK][BN + 4];
    int n0 = blockIdx.x * BN;
    int m0 = blockIdx.y * BM;
    const float* Bp = B0;
    const float* bias = bias0;
    int nb = n0, ldb = N;
    if (segmented) {
        int seg = n0 >> 7;
        Bp = (seg == 0) ? B0 : ((seg == 1) ? B1 : B2);
        bias = (seg == 0) ? bias0 : ((seg == 1) ? bias1 : bias2);
        nb = n0 - (seg << 7);
        ldb = 128;
    }
    int tid = threadIdx.x;
    int tx = tid & 15, ty = tid >> 4;
    int ac = tid & 15, ar4 = tid >> 4;   // A tile: 16 k-cols x 16 m-rows per pass
    int bc = tid & 63, br4 = tid >> 6;   // B tile: 4 k-rows x 64 n-cols per pass
    float acc[4][4] = {{0.f}};
    for (int k0 = 0; k0 < K; k0 += BK) {
#pragma unroll
        for (int it = 0; it < 4; ++it)
            As[ac][ar4 + 16 * it] = A[(size_t)(m0 + ar4 + 16 * it) * K + (k0 + ac)];
#pragma unroll
        for (int it = 0; it < 4; ++it)
            Bs[br4 + 4 * it][bc] = Bp[(size_t)(k0 + br4 + 4 * it) * ldb + (nb + bc)];
        __syncthreads();
#pragma unroll
        for (int kk = 0; kk < BK; ++kk) {
            float a[4], bv[4];
#pragma unroll
            for (int i = 0; i < 4; ++i) a[i] = As[kk][ty * 4 + i];
#pragma unroll
            for (int j = 0; j < 4; ++j) bv[j] = Bs[kk][tx * 4 + j];
#pragma unroll
            for (int i = 0; i < 4; ++i)
#pragma unroll
                for (int j = 0; j < 4; ++j)
                    acc[i][j] = fmaf(a[i], bv[j], acc[i][j]);
        }
        __syncthreads();
    }
#pragma unroll
    for (int i = 0; i < 4; ++i) {
        int m = m0 + ty * 4 + i;
        int n = n0 + tx * 4;
        float4 r = make_float4(acc[i][0], acc[i][1], acc[i][2], acc[i][3]);
        if (bias) {
            int bn = nb + tx * 4;
            r.x += bias[bn]; r.y += bias[bn + 1]; r.z += bias[bn + 2]; r.w += bias[bn + 3];
        }
        if (addmat) {
            const float4 av = *(const float4*)(addmat + (size_t)m * N + n);
            if (addscale) {
                const float4 sc = *(const float4*)(addscale + n);
                r.x += sc.x * av.x; r.y += sc.y * av.y; r.z += sc.z * av.z; r.w += sc.w * av.w;
            } else {
                r.x += av.x; r.y += av.y; r.z += av.z; r.w += av.w;
            }
        }
        *(float4*)(C + (size_t)m * N + n) = r;
    }
}

// ---------------- Chunked linear scan (replaces FFT conv exactly) ----------------
// h[t] = a_s*h[t-1] + u[t],  a_s = exp(-exp(A_log[s])),  u = x_state * B_sel
// Phase 1: per-chunk local scan; store local h and chunk-end value E.
__global__ __launch_bounds__(128) void scan_p1(const float* __restrict__ s3,
                                               const float* __restrict__ A_log,
                                               float* __restrict__ hbuf,
                                               float* __restrict__ Ebuf) {
    int s = threadIdx.x;
    int c = blockIdx.x, b = blockIdx.y;
    float a = expf(-expf(A_log[s]));
    float h = 0.f;
    size_t base = (size_t)b * SEQ_LEN + (size_t)c * LCHUNK;
    for (int i = 0; i < LCHUNK; ++i) {
        size_t r = base + i;
        float u = s3[r * 384 + s] * s3[r * 384 + 128 + s];
        h = a * h + u;
        hbuf[r * 128 + s] = h;
    }
    Ebuf[((size_t)b * NCHUNK + c) * 128 + s] = h;
}

// Phase 2: sequential prefix over the 64 chunk summaries, per (b,s).
__global__ __launch_bounds__(512) void scan_p2(const float* __restrict__ A_log,
                                               const float* __restrict__ Ebuf,
                                               float* __restrict__ Gbuf) {
    int tid = threadIdx.x;   // 0..511
    int b = tid >> 7, s = tid & 127;
    float A = -expf(A_log[s]);
    float pw = expf(A * (float)LCHUNK);   // a^LCHUNK, exact
    float G = 0.f;
    for (int c = 0; c < NCHUNK; ++c) {
        size_t idx = ((size_t)b * NCHUNK + c) * 128 + s;
        G = pw * G + Ebuf[idx];
        Gbuf[idx] = G;
    }
}

// Phase 3: apply carry-in, multiply by C_sel -> ys (A-matrix for W_so GEMM).
__global__ __launch_bounds__(128) void scan_p3(const float* __restrict__ s3,
                                               const float* __restrict__ A_log,
                                               const float* __restrict__ hbuf,
                                               const float* __restrict__ Gbuf,
                                               float* __restrict__ ys) {
    int s = threadIdx.x;
    int c = blockIdx.x, b = blockIdx.y;
    float a = expf(-expf(A_log[s]));
    float carry = (c == 0) ? 0.f : Gbuf[((size_t)b * NCHUNK + c - 1) * 128 + s];
    float p = a;
    size_t base = (size_t)b * SEQ_LEN + (size_t)c * LCHUNK;
    for (int i = 0; i < LCHUNK; ++i) {
        size_t r = base + i;
        float h = hbuf[r * 128 + s] + p * carry;
        p *= a;
        ys[r * 128 + s] = h * s3[r * 384 + 256 + s];
    }
}

extern "C" void kernel_launch(void* const* d_in, const int* in_sizes, int n_in,
                              void* d_out, int out_size, void* d_ws, size_t ws_size,
                              hipStream_t stream) {
    const float* x     = (const float*)d_in[0];
    const float* ln_g  = (const float*)d_in[1];
    const float* ln_b  = (const float*)d_in[2];
    const float* W_in  = (const float*)d_in[3];
    const float* b_in  = (const float*)d_in[4];
    const float* W_xs  = (const float*)d_in[5];
    const float* W_B   = (const float*)d_in[6];
    const float* b_B   = (const float*)d_in[7];
    const float* W_C   = (const float*)d_in[8];
    const float* b_C   = (const float*)d_in[9];
    const float* A_log = (const float*)d_in[10];
    const float* Dvec  = (const float*)d_in[11];
    const float* W_so  = (const float*)d_in[12];
    const float* W_out = (const float*)d_in[13];
    const float* b_out = (const float*)d_in[14];
    float* out = (float*)d_out;

    float* ws = (float*)d_ws;
    size_t off = 0;
    float* xn   = ws + off; off += (size_t)NTOK * D_MODEL;   // reused as y1 later
    float* z    = ws + off; off += (size_t)NTOK * D_MODEL;
    float* s3   = ws + off; off += (size_t)NTOK * 384;
    float* hbuf = ws + off; off += (size_t)NTOK * D_STATE;
    float* ys   = ws + off; off += (size_t)NTOK * D_STATE;
    float* Ebuf = ws + off; off += (size_t)BATCH * NCHUNK * D_STATE;
    float* Gbuf = ws + off; off += (size_t)BATCH * NCHUNK * D_STATE;
    float* y1 = xn;   // xn dead after GEMM1; alias

    // 1) LayerNorm
    ln_kernel<<<NTOK, 256, 0, stream>>>(x, ln_g, ln_b, xn);

    // 2) z = xn @ W_in + b_in
    dim3 g1(D_MODEL / BN, NTOK / BM);
    gemm_kernel<<<g1, 256, 0, stream>>>(xn, W_in, W_in, W_in, b_in, b_in, b_in,
                                        nullptr, nullptr, z, NTOK, D_MODEL, D_MODEL, 0);

    // 3) s3 = z @ [W_xs | W_B | W_C] (+ [0 | b_B | b_C])
    dim3 g2(384 / BN, NTOK / BM);
    gemm_kernel<<<g2, 256, 0, stream>>>(z, W_xs, W_B, W_C, nullptr, b_B, b_C,
                                        nullptr, nullptr, s3, NTOK, 384, D_MODEL, 1);

    // 4) chunked scan (exact replacement of FFT causal conv), fused *C_sel
    scan_p1<<<dim3(NCHUNK, BATCH), 128, 0, stream>>>(s3, A_log, hbuf, Ebuf);
    scan_p2<<<1, 512, 0, stream>>>(A_log, Ebuf, Gbuf);
    scan_p3<<<dim3(NCHUNK, BATCH), 128, 0, stream>>>(s3, A_log, hbuf, Gbuf, ys);

    // 5) y1 = ys @ W_so + D*z
    gemm_kernel<<<g1, 256, 0, stream>>>(ys, W_so, W_so, W_so, nullptr, nullptr, nullptr,
                                        z, Dvec, y1, NTOK, D_MODEL, D_STATE, 0);

    // 6) out = y1 @ W_out + b_out + x (residual)
    gemm_kernel<<<g1, 256, 0, stream>>>(y1, W_out, W_out, W_out, b_out, b_out, b_out,
                                        x, nullptr, out, NTOK, D_MODEL, D_MODEL, 0);
}

// Round 2
// 371.827 us; speedup vs baseline: 3.5867x; 3.5867x over previous
//
#include <hip/hip_runtime.h>
#include <math.h>

#define D_MODEL 1024
#define D_STATE 128
#define SEQ_LEN 4096
#define BATCH 4
#define NTOK (BATCH * SEQ_LEN)      // 16384
#define LN_EPS 1e-3f
#define NCHUNK 64
#define LCHUNK (SEQ_LEN / NCHUNK)   // 64

typedef __attribute__((ext_vector_type(8))) short bf16x8;
typedef __attribute__((ext_vector_type(4))) float f32x4;

__device__ __forceinline__ short f2bf(float f) {
    union { float f; unsigned u; } v; v.f = f;
    unsigned r = v.u + 0x7FFFu + ((v.u >> 16) & 1u);   // RNE
    return (short)(r >> 16);
}

// ---------------- LayerNorm -> bf16 output ----------------
__global__ __launch_bounds__(256) void ln_kernel(const float* __restrict__ x,
                                                 const float* __restrict__ gamma,
                                                 const float* __restrict__ beta,
                                                 short* __restrict__ xn_bf) {
    int row = blockIdx.x;
    const float4* xr = (const float4*)(x + (size_t)row * D_MODEL);
    float4 v = xr[threadIdx.x];
    float s1 = v.x + v.y + v.z + v.w;
    float s2 = v.x * v.x + v.y * v.y + v.z * v.z + v.w * v.w;
    for (int off = 32; off; off >>= 1) {
        s1 += __shfl_down(s1, off);
        s2 += __shfl_down(s2, off);
    }
    __shared__ float ls1[4], ls2[4];
    int wid = threadIdx.x >> 6, lane = threadIdx.x & 63;
    if (lane == 0) { ls1[wid] = s1; ls2[wid] = s2; }
    __syncthreads();
    s1 = ls1[0] + ls1[1] + ls1[2] + ls1[3];
    s2 = ls2[0] + ls2[1] + ls2[2] + ls2[3];
    float mu = s1 * (1.0f / D_MODEL);
    float var = s2 * (1.0f / D_MODEL) - mu * mu;
    float r = rsqrtf(var + LN_EPS);
    float4 g = ((const float4*)gamma)[threadIdx.x];
    float4 b = ((const float4*)beta)[threadIdx.x];
    short4 o;
    o.x = f2bf((v.x - mu) * r * g.x + b.x);
    o.y = f2bf((v.y - mu) * r * g.y + b.y);
    o.z = f2bf((v.z - mu) * r * g.z + b.z);
    o.w = f2bf((v.w - mu) * r * g.w + b.w);
    ((short4*)(xn_bf + (size_t)row * D_MODEL))[threadIdx.x] = o;
}

// ---------------- transpose + fp32->bf16: out[n][k] = in[k][n] ----------------
__global__ __launch_bounds__(256) void transpose_bf(const float* __restrict__ in,
                                                    short* __restrict__ out,
                                                    int K, int N) {
    __shared__ float t[32][33];
    int nb = blockIdx.x * 32, kb = blockIdx.y * 32;
    int tx = threadIdx.x, ty = threadIdx.y;   // 32 x 8
#pragma unroll
    for (int i = 0; i < 4; ++i)
        t[ty + 8 * i][tx] = in[(size_t)(kb + ty + 8 * i) * N + nb + tx];
    __syncthreads();
#pragma unroll
    for (int i = 0; i < 4; ++i)
        out[(size_t)(nb + ty + 8 * i) * K + kb + tx] = f2bf(t[tx][ty + 8 * i]);
}

__global__ void build_bias3(const float* __restrict__ bB, const float* __restrict__ bC,
                            float* __restrict__ bias3) {
    int n = blockIdx.x * 128 + threadIdx.x;   // <<<3,128>>>
    bias3[n] = (n < 128) ? 0.f : ((n < 256) ? bB[n - 128] : bC[n - 256]);
}

// ---------------- bf16 MFMA GEMM, m97 structure ----------------
// C[M,N] = A[M,K](bf16) @ BT[N,K](bf16)^T, fp32 accum.
// Epilogue: (+bias[n]) (+addscale[n]*addmat[m,n] or +addmat) -> Cf(f32) and/or Cbf(bf16)
template<int HAS_BIAS, int HAS_ADD, int HAS_SCALE, int OUT_F32, int OUT_BF>
__global__ __launch_bounds__(256) void gemm_bf16(
    const short* __restrict__ A, const short* __restrict__ BT,
    const float* __restrict__ bias,
    const float* __restrict__ addmat, const float* __restrict__ addscale,
    float* __restrict__ Cf, short* __restrict__ Cbf,
    int M, int N, int K) {
    __shared__ short As[128 * 32];   // [m][k] row-major, no pad (global_load_lds order)
    __shared__ short Bs[128 * 32];   // [n][k]
    int m0 = blockIdx.y * 128;
    int n0 = blockIdx.x * 128;
    int tid = threadIdx.x;
    int lane = tid & 63;
    int w = tid >> 6;
    int quad = lane >> 4, r16 = lane & 15;
    int wm = (w & 1) * 64, wn = (w >> 1) * 64;

    f32x4 acc[4][4] = {};

    for (int k0 = 0; k0 < K; k0 += 32) {
#pragma unroll
        for (int it = 0; it < 2; ++it) {
            int seg = it * 256 + tid;
            int row = seg >> 2, sc = seg & 3;
            const short* gp = A + (size_t)(m0 + row) * K + k0 + sc * 8;
            __builtin_amdgcn_global_load_lds(
                (const __attribute__((address_space(1))) unsigned*)gp,
                (__attribute__((address_space(3))) unsigned*)(As + seg * 8), 16, 0, 0);
        }
#pragma unroll
        for (int it = 0; it < 2; ++it) {
            int seg = it * 256 + tid;
            int row = seg >> 2, sc = seg & 3;
            const short* gp = BT + (size_t)(n0 + row) * K + k0 + sc * 8;
            __builtin_amdgcn_global_load_lds(
                (const __attribute__((address_space(1))) unsigned*)gp,
                (__attribute__((address_space(3))) unsigned*)(Bs + seg * 8), 16, 0, 0);
        }
        __syncthreads();   // drains vmcnt (global_load_lds) + lgkmcnt

        const short* ap = As + (wm + r16) * 32 + quad * 8;
        const short* bp = Bs + (wn + r16) * 32 + quad * 8;
        bf16x8 af[4], bfr[4];
#pragma unroll
        for (int i = 0; i < 4; ++i) af[i] = *(const bf16x8*)(ap + i * 16 * 32);
#pragma unroll
        for (int j = 0; j < 4; ++j) bfr[j] = *(const bf16x8*)(bp + j * 16 * 32);
#pragma unroll
        for (int i = 0; i < 4; ++i)
#pragma unroll
            for (int j = 0; j < 4; ++j)
                acc[i][j] = __builtin_amdgcn_mfma_f32_16x16x32_bf16(af[i], bfr[j], acc[i][j], 0, 0, 0);
        __syncthreads();
    }

#pragma unroll
    for (int i = 0; i < 4; ++i) {
#pragma unroll
        for (int j = 0; j < 4; ++j) {
            int col = n0 + wn + j * 16 + r16;
            float bv = HAS_BIAS ? bias[col] : 0.f;
            float sc = HAS_SCALE ? addscale[col] : 1.f;
#pragma unroll
            for (int p = 0; p < 4; ++p) {
                int row = m0 + wm + i * 16 + quad * 4 + p;
                float v = acc[i][j][p] + bv;
                if (HAS_ADD) v += sc * addmat[(size_t)row * N + col];
                if (OUT_F32) Cf[(size_t)row * N + col] = v;
                if (OUT_BF) Cbf[(size_t)row * N + col] = f2bf(v);
            }
        }
    }
}

// ---------------- Chunked linear scan (exact FFT-conv replacement) ----------------
__global__ __launch_bounds__(128) void scan_p1(const float* __restrict__ s3,
                                               const float* __restrict__ A_log,
                                               float* __restrict__ hbuf,
                                               float* __restrict__ Ebuf) {
    int s = threadIdx.x;
    int c = blockIdx.x, b = blockIdx.y;
    float a = expf(-expf(A_log[s]));
    float h = 0.f;
    size_t base = (size_t)b * SEQ_LEN + (size_t)c * LCHUNK;
    for (int i = 0; i < LCHUNK; ++i) {
        size_t r = base + i;
        float u = s3[r * 384 + s] * s3[r * 384 + 128 + s];
        h = a * h + u;
        hbuf[r * 128 + s] = h;
    }
    Ebuf[((size_t)b * NCHUNK + c) * 128 + s] = h;
}

__global__ __launch_bounds__(512) void scan_p2(const float* __restrict__ A_log,
                                               const float* __restrict__ Ebuf,
                                               float* __restrict__ Gbuf) {
    int tid = threadIdx.x;
    int b = tid >> 7, s = tid & 127;
    float A = -expf(A_log[s]);
    float pw = expf(A * (float)LCHUNK);
    float G = 0.f;
    for (int c = 0; c < NCHUNK; ++c) {
        size_t idx = ((size_t)b * NCHUNK + c) * 128 + s;
        G = pw * G + Ebuf[idx];
        Gbuf[idx] = G;
    }
}

__global__ __launch_bounds__(128) void scan_p3(const float* __restrict__ s3,
                                               const float* __restrict__ A_log,
                                               const float* __restrict__ hbuf,
                                               const float* __restrict__ Gbuf,
                                               short* __restrict__ ys_bf) {
    int s = threadIdx.x;
    int c = blockIdx.x, b = blockIdx.y;
    float a = expf(-expf(A_log[s]));
    float carry = (c == 0) ? 0.f : Gbuf[((size_t)b * NCHUNK + c - 1) * 128 + s];
    float p = a;
    size_t base = (size_t)b * SEQ_LEN + (size_t)c * LCHUNK;
    for (int i = 0; i < LCHUNK; ++i) {
        size_t r = base + i;
        float h = hbuf[r * 128 + s] + p * carry;
        p *= a;
        ys_bf[r * 128 + s] = f2bf(h * s3[r * 384 + 256 + s]);
    }
}

extern "C" void kernel_launch(void* const* d_in, const int* in_sizes, int n_in,
                              void* d_out, int out_size, void* d_ws, size_t ws_size,
                              hipStream_t stream) {
    const float* x     = (const float*)d_in[0];
    const float* ln_g  = (const float*)d_in[1];
    const float* ln_b  = (const float*)d_in[2];
    const float* W_in  = (const float*)d_in[3];
    const float* b_in  = (const float*)d_in[4];
    const float* W_xs  = (const float*)d_in[5];
    const float* W_B   = (const float*)d_in[6];
    const float* b_B   = (const float*)d_in[7];
    const float* W_C   = (const float*)d_in[8];
    const float* b_C   = (const float*)d_in[9];
    const float* A_log = (const float*)d_in[10];
    const float* Dvec  = (const float*)d_in[11];
    const float* W_so  = (const float*)d_in[12];
    const float* W_out = (const float*)d_in[13];
    const float* b_out = (const float*)d_in[14];
    float* out = (float*)d_out;

    // ---- workspace carve (bytes) ----
    char* w = (char*)d_ws;
    size_t off = 0;
    short* xn_bf = (short*)(w + off);                       // 32 MiB region 0
    float* hbuf  = (float*)(w + off);                       //   reuses region 0 after GEMM1
    short* ys_bf = (short*)(w + off + 8388608);             //   after hbuf
    off += (size_t)NTOK * D_MODEL * 2;                      // 33554432
    float* z     = (float*)(w + off); off += (size_t)NTOK * D_MODEL * 4;   // 64 MiB
    short* z_bf  = (short*)(w + off);                       // 32 MiB region 2
    short* y1_bf = z_bf;                                    //   reuse after GEMM2
    off += (size_t)NTOK * D_MODEL * 2;
    float* s3    = (float*)(w + off); off += (size_t)NTOK * 384 * 4;       // 24 MiB
    float* Ebuf  = (float*)(w + off); off += (size_t)BATCH * NCHUNK * 128 * 4;
    float* Gbuf  = (float*)(w + off); off += (size_t)BATCH * NCHUNK * 128 * 4;
    short* W_inT  = (short*)(w + off); off += (size_t)D_MODEL * D_MODEL * 2;
    short* W3T    = (short*)(w + off); off += (size_t)384 * D_MODEL * 2;
    short* W_soT  = (short*)(w + off); off += (size_t)D_MODEL * D_STATE * 2;
    short* W_outT = (short*)(w + off); off += (size_t)D_MODEL * D_MODEL * 2;
    float* bias3  = (float*)(w + off); off += 2048;

    // ---- weight prep (bf16, transposed) ----
    dim3 tb(32, 8);
    transpose_bf<<<dim3(D_MODEL / 32, D_MODEL / 32), tb, 0, stream>>>(W_in, W_inT, D_MODEL, D_MODEL);
    transpose_bf<<<dim3(D_STATE / 32, D_MODEL / 32), tb, 0, stream>>>(W_xs, W3T, D_MODEL, D_STATE);
    transpose_bf<<<dim3(D_STATE / 32, D_MODEL / 32), tb, 0, stream>>>(W_B, W3T + 128 * D_MODEL, D_MODEL, D_STATE);
    transpose_bf<<<dim3(D_STATE / 32, D_MODEL / 32), tb, 0, stream>>>(W_C, W3T + 256 * D_MODEL, D_MODEL, D_STATE);
    transpose_bf<<<dim3(D_MODEL / 32, D_STATE / 32), tb, 0, stream>>>(W_so, W_soT, D_STATE, D_MODEL);
    transpose_bf<<<dim3(D_MODEL / 32, D_MODEL / 32), tb, 0, stream>>>(W_out, W_outT, D_MODEL, D_MODEL);
    build_bias3<<<3, 128, 0, stream>>>(b_B, b_C, bias3);

    // ---- 1) LayerNorm -> bf16 ----
    ln_kernel<<<NTOK, 256, 0, stream>>>(x, ln_g, ln_b, xn_bf);

    // ---- 2) z = xn @ W_in + b_in  (f32 + bf16 outputs) ----
    dim3 g1(D_MODEL / 128, NTOK / 128);
    gemm_bf16<1, 0, 0, 1, 1><<<g1, 256, 0, stream>>>(xn_bf, W_inT, b_in, nullptr, nullptr,
                                                     z, z_bf, NTOK, D_MODEL, D_MODEL);

    // ---- 3) s3 = z @ [W_xs|W_B|W_C] + bias3  (f32) ----
    dim3 g2(384 / 128, NTOK / 128);
    gemm_bf16<1, 0, 0, 1, 0><<<g2, 256, 0, stream>>>(z_bf, W3T, bias3, nullptr, nullptr,
                                                     s3, nullptr, NTOK, 384, D_MODEL);

    // ---- 4) chunked scan (fp32 exact), fused *C_sel -> ys_bf ----
    scan_p1<<<dim3(NCHUNK, BATCH), 128, 0, stream>>>(s3, A_log, hbuf, Ebuf);
    scan_p2<<<1, 512, 0, stream>>>(A_log, Ebuf, Gbuf);
    scan_p3<<<dim3(NCHUNK, BATCH), 128, 0, stream>>>(s3, A_log, hbuf, Gbuf, ys_bf);

    // ---- 5) y1 = ys @ W_so + D*z  (bf16 out) ----
    gemm_bf16<0, 1, 1, 0, 1><<<g1, 256, 0, stream>>>(ys_bf, W_soT, nullptr, z, Dvec,
                                                     nullptr, y1_bf, NTOK, D_MODEL, D_STATE);

    // ---- 6) out = y1 @ W_out + b_out + x ----
    gemm_bf16<1, 1, 0, 1, 0><<<g1, 256, 0, stream>>>(y1_bf, W_outT, b_out, x, nullptr,
                                                     out, nullptr, NTOK, D_MODEL, D_MODEL);
}

// Round 3
// 337.952 us; speedup vs baseline: 3.9462x; 1.1002x over previous
//
#include <hip/hip_runtime.h>
#include <math.h>

#define D_MODEL 1024
#define D_STATE 128
#define SEQ_LEN 4096
#define BATCH 4
#define NTOK (BATCH * SEQ_LEN)      // 16384
#define LN_EPS 1e-3f
#define NCHUNK 64
#define LCHUNK (SEQ_LEN / NCHUNK)   // 64

typedef __attribute__((ext_vector_type(8))) short bf16x8;
typedef __attribute__((ext_vector_type(4))) float f32x4;

__device__ __forceinline__ short f2bf(float f) {
    union { float f; unsigned u; } v; v.f = f;
    unsigned r = v.u + 0x7FFFu + ((v.u >> 16) & 1u);   // RNE
    return (short)(r >> 16);
}
__device__ __forceinline__ float bf2f(short s) {
    union { unsigned u; float f; } v; v.u = ((unsigned)(unsigned short)s) << 16;
    return v.f;
}

// ---------------- LayerNorm -> bf16 output ----------------
__global__ __launch_bounds__(256) void ln_kernel(const float* __restrict__ x,
                                                 const float* __restrict__ gamma,
                                                 const float* __restrict__ beta,
                                                 short* __restrict__ xn_bf) {
    int row = blockIdx.x;
    const float4* xr = (const float4*)(x + (size_t)row * D_MODEL);
    float4 v = xr[threadIdx.x];
    float s1 = v.x + v.y + v.z + v.w;
    float s2 = v.x * v.x + v.y * v.y + v.z * v.z + v.w * v.w;
    for (int off = 32; off; off >>= 1) {
        s1 += __shfl_down(s1, off);
        s2 += __shfl_down(s2, off);
    }
    __shared__ float ls1[4], ls2[4];
    int wid = threadIdx.x >> 6, lane = threadIdx.x & 63;
    if (lane == 0) { ls1[wid] = s1; ls2[wid] = s2; }
    __syncthreads();
    s1 = ls1[0] + ls1[1] + ls1[2] + ls1[3];
    s2 = ls2[0] + ls2[1] + ls2[2] + ls2[3];
    float mu = s1 * (1.0f / D_MODEL);
    float var = s2 * (1.0f / D_MODEL) - mu * mu;
    float r = rsqrtf(var + LN_EPS);
    float4 g = ((const float4*)gamma)[threadIdx.x];
    float4 b = ((const float4*)beta)[threadIdx.x];
    short4 o;
    o.x = f2bf((v.x - mu) * r * g.x + b.x);
    o.y = f2bf((v.y - mu) * r * g.y + b.y);
    o.z = f2bf((v.z - mu) * r * g.z + b.z);
    o.w = f2bf((v.w - mu) * r * g.w + b.w);
    ((short4*)(xn_bf + (size_t)row * D_MODEL))[threadIdx.x] = o;
}

// ---------------- transpose + fp32->bf16: out[n][k] = in[k][n] ----------------
__global__ __launch_bounds__(256) void transpose_bf(const float* __restrict__ in,
                                                    short* __restrict__ out,
                                                    int K, int N) {
    __shared__ float t[32][33];
    int nb = blockIdx.x * 32, kb = blockIdx.y * 32;
    int tx = threadIdx.x, ty = threadIdx.y;   // 32 x 8
#pragma unroll
    for (int i = 0; i < 4; ++i)
        t[ty + 8 * i][tx] = in[(size_t)(kb + ty + 8 * i) * N + nb + tx];
    __syncthreads();
#pragma unroll
    for (int i = 0; i < 4; ++i)
        out[(size_t)(nb + ty + 8 * i) * K + kb + tx] = f2bf(t[tx][ty + 8 * i]);
}

__global__ void build_bias3(const float* __restrict__ bB, const float* __restrict__ bC,
                            float* __restrict__ bias3) {
    int n = blockIdx.x * 128 + threadIdx.x;   // <<<3,128>>>
    bias3[n] = (n < 128) ? 0.f : ((n < 256) ? bB[n - 128] : bC[n - 256]);
}

// ---------------- bf16 MFMA GEMM, m97 structure + XCD swizzle ----------------
// C[M,N] = A[M,K](bf16) @ BT[N,K](bf16)^T, fp32 accum. 1-D grid of Mt*Nt tiles.
// SWZ=1 (requires Mt%8==0, Nt==8): same-m-tile blocks land on one XCD.
template<int HAS_BIAS, int HAS_ADD, int ADD_BF, int HAS_SCALE, int OUT_F32, int OUT_BF, int SWZ>
__global__ __launch_bounds__(256) void gemm_bf16(
    const short* __restrict__ A, const short* __restrict__ BT,
    const float* __restrict__ bias,
    const float* __restrict__ addf, const short* __restrict__ addb,
    const float* __restrict__ addscale,
    float* __restrict__ Cf, short* __restrict__ Cbf,
    int Mt, int Nt, int K) {
    __shared__ short As[128 * 32];   // [m][k] row-major (global_load_lds order)
    __shared__ short Bs[128 * 32];   // [n][k]
    int p = blockIdx.x;
    int mtile, ntile;
    if (SWZ) {           // xcd = p&7; each XCD runs (m, n=0..7) consecutively
        int k = p & 7, q = p >> 3;
        ntile = q & 7;
        mtile = k + 8 * (q >> 3);
    } else {
        mtile = p % Mt;
        ntile = p / Mt;
    }
    int m0 = mtile * 128, n0 = ntile * 128;
    int N = Nt * 128;
    int tid = threadIdx.x;
    int lane = tid & 63;
    int w = tid >> 6;
    int quad = lane >> 4, r16 = lane & 15;
    int wm = (w & 1) * 64, wn = (w >> 1) * 64;

    f32x4 acc[4][4] = {};

    for (int k0 = 0; k0 < K; k0 += 32) {
#pragma unroll
        for (int it = 0; it < 2; ++it) {
            int seg = it * 256 + tid;
            int row = seg >> 2, sc = seg & 3;
            const short* gp = A + (size_t)(m0 + row) * K + k0 + sc * 8;
            __builtin_amdgcn_global_load_lds(
                (const __attribute__((address_space(1))) unsigned*)gp,
                (__attribute__((address_space(3))) unsigned*)(As + seg * 8), 16, 0, 0);
        }
#pragma unroll
        for (int it = 0; it < 2; ++it) {
            int seg = it * 256 + tid;
            int row = seg >> 2, sc = seg & 3;
            const short* gp = BT + (size_t)(n0 + row) * K + k0 + sc * 8;
            __builtin_amdgcn_global_load_lds(
                (const __attribute__((address_space(1))) unsigned*)gp,
                (__attribute__((address_space(3))) unsigned*)(Bs + seg * 8), 16, 0, 0);
        }
        __syncthreads();

        const short* ap = As + (wm + r16) * 32 + quad * 8;
        const short* bp = Bs + (wn + r16) * 32 + quad * 8;
        bf16x8 af[4], bfr[4];
#pragma unroll
        for (int i = 0; i < 4; ++i) af[i] = *(const bf16x8*)(ap + i * 16 * 32);
#pragma unroll
        for (int j = 0; j < 4; ++j) bfr[j] = *(const bf16x8*)(bp + j * 16 * 32);
#pragma unroll
        for (int i = 0; i < 4; ++i)
#pragma unroll
            for (int j = 0; j < 4; ++j)
                acc[i][j] = __builtin_amdgcn_mfma_f32_16x16x32_bf16(af[i], bfr[j], acc[i][j], 0, 0, 0);
        __syncthreads();
    }

#pragma unroll
    for (int i = 0; i < 4; ++i) {
#pragma unroll
        for (int j = 0; j < 4; ++j) {
            int col = n0 + wn + j * 16 + r16;
            float bv = HAS_BIAS ? bias[col] : 0.f;
            float sc = HAS_SCALE ? addscale[col] : 1.f;
#pragma unroll
            for (int pr = 0; pr < 4; ++pr) {
                int row = m0 + wm + i * 16 + quad * 4 + pr;
                float v = acc[i][j][pr] + bv;
                if (HAS_ADD) {
                    float av = ADD_BF ? bf2f(addb[(size_t)row * N + col])
                                      : addf[(size_t)row * N + col];
                    v += sc * av;
                }
                if (OUT_F32) Cf[(size_t)row * N + col] = v;
                if (OUT_BF) Cbf[(size_t)row * N + col] = f2bf(v);
            }
        }
    }
}

// ---------------- Chunked linear scan (exact FFT-conv replacement) ----------------
__global__ __launch_bounds__(128) void scan_p1(const float* __restrict__ s3,
                                               const float* __restrict__ A_log,
                                               float* __restrict__ hbuf,
                                               float* __restrict__ Ebuf) {
    int s = threadIdx.x;
    int c = blockIdx.x, b = blockIdx.y;
    float a = expf(-expf(A_log[s]));
    float h = 0.f;
    size_t base = (size_t)b * SEQ_LEN + (size_t)c * LCHUNK;
    for (int i = 0; i < LCHUNK; ++i) {
        size_t r = base + i;
        float u = s3[r * 384 + s] * s3[r * 384 + 128 + s];
        h = a * h + u;
        hbuf[r * 128 + s] = h;
    }
    Ebuf[((size_t)b * NCHUNK + c) * 128 + s] = h;
}

__global__ __launch_bounds__(512) void scan_p2(const float* __restrict__ A_log,
                                               const float* __restrict__ Ebuf,
                                               float* __restrict__ Gbuf) {
    int tid = threadIdx.x;
    int b = tid >> 7, s = tid & 127;
    float A = -expf(A_log[s]);
    float pw = expf(A * (float)LCHUNK);
    float e[NCHUNK];
#pragma unroll
    for (int c = 0; c < NCHUNK; ++c)
        e[c] = Ebuf[((size_t)b * NCHUNK + c) * 128 + s];
    float G = 0.f;
#pragma unroll
    for (int c = 0; c < NCHUNK; ++c) {
        G = pw * G + e[c];
        Gbuf[((size_t)b * NCHUNK + c) * 128 + s] = G;
    }
}

__global__ __launch_bounds__(128) void scan_p3(const float* __restrict__ s3,
                                               const float* __restrict__ A_log,
                                               const float* __restrict__ hbuf,
                                               const float* __restrict__ Gbuf,
                                               short* __restrict__ ys_bf) {
    int s = threadIdx.x;
    int c = blockIdx.x, b = blockIdx.y;
    float a = expf(-expf(A_log[s]));
    float carry = (c == 0) ? 0.f : Gbuf[((size_t)b * NCHUNK + c - 1) * 128 + s];
    float p = a;
    size_t base = (size_t)b * SEQ_LEN + (size_t)c * LCHUNK;
    for (int i = 0; i < LCHUNK; ++i) {
        size_t r = base + i;
        float h = hbuf[r * 128 + s] + p * carry;
        p *= a;
        ys_bf[r * 128 + s] = f2bf(h * s3[r * 384 + 256 + s]);
    }
}

extern "C" void kernel_launch(void* const* d_in, const int* in_sizes, int n_in,
                              void* d_out, int out_size, void* d_ws, size_t ws_size,
                              hipStream_t stream) {
    const float* x     = (const float*)d_in[0];
    const float* ln_g  = (const float*)d_in[1];
    const float* ln_b  = (const float*)d_in[2];
    const float* W_in  = (const float*)d_in[3];
    const float* b_in  = (const float*)d_in[4];
    const float* W_xs  = (const float*)d_in[5];
    const float* W_B   = (const float*)d_in[6];
    const float* b_B   = (const float*)d_in[7];
    const float* W_C   = (const float*)d_in[8];
    const float* b_C   = (const float*)d_in[9];
    const float* A_log = (const float*)d_in[10];
    const float* Dvec  = (const float*)d_in[11];
    const float* W_so  = (const float*)d_in[12];
    const float* W_out = (const float*)d_in[13];
    const float* b_out = (const float*)d_in[14];
    float* out = (float*)d_out;

    // ---- workspace carve (bytes) ----
    char* w = (char*)d_ws;
    size_t off = 0;
    short* xn_bf = (short*)(w + off);                       // region 0: 32 MiB
    float* hbuf  = (float*)(w + off);                       //   reuses region 0 after GEMM1
    short* ys_bf = (short*)(w + off + 8388608);             //   after hbuf (8 MiB)
    off += (size_t)NTOK * D_MODEL * 2;
    short* z_bf  = (short*)(w + off);                       // region 1: 32 MiB
    off += (size_t)NTOK * D_MODEL * 2;
    short* y1_bf = (short*)(w + off);                       // region 2: 32 MiB
    off += (size_t)NTOK * D_MODEL * 2;
    float* s3    = (float*)(w + off); off += (size_t)NTOK * 384 * 4;       // 24 MiB
    float* Ebuf  = (float*)(w + off); off += (size_t)BATCH * NCHUNK * 128 * 4;
    float* Gbuf  = (float*)(w + off); off += (size_t)BATCH * NCHUNK * 128 * 4;
    short* W_inT  = (short*)(w + off); off += (size_t)D_MODEL * D_MODEL * 2;
    short* W3T    = (short*)(w + off); off += (size_t)384 * D_MODEL * 2;
    short* W_soT  = (short*)(w + off); off += (size_t)D_MODEL * D_STATE * 2;
    short* W_outT = (short*)(w + off); off += (size_t)D_MODEL * D_MODEL * 2;
    float* bias3  = (float*)(w + off); off += 2048;

    // ---- weight prep (bf16, transposed) ----
    dim3 tb(32, 8);
    transpose_bf<<<dim3(D_MODEL / 32, D_MODEL / 32), tb, 0, stream>>>(W_in, W_inT, D_MODEL, D_MODEL);
    transpose_bf<<<dim3(D_STATE / 32, D_MODEL / 32), tb, 0, stream>>>(W_xs, W3T, D_MODEL, D_STATE);
    transpose_bf<<<dim3(D_STATE / 32, D_MODEL / 32), tb, 0, stream>>>(W_B, W3T + 128 * D_MODEL, D_MODEL, D_STATE);
    transpose_bf<<<dim3(D_STATE / 32, D_MODEL / 32), tb, 0, stream>>>(W_C, W3T + 256 * D_MODEL, D_MODEL, D_STATE);
    transpose_bf<<<dim3(D_MODEL / 32, D_STATE / 32), tb, 0, stream>>>(W_so, W_soT, D_STATE, D_MODEL);
    transpose_bf<<<dim3(D_MODEL / 32, D_MODEL / 32), tb, 0, stream>>>(W_out, W_outT, D_MODEL, D_MODEL);
    build_bias3<<<3, 128, 0, stream>>>(b_B, b_C, bias3);

    // ---- 1) LayerNorm -> bf16 ----
    ln_kernel<<<NTOK, 256, 0, stream>>>(x, ln_g, ln_b, xn_bf);

    const int Mt = NTOK / 128;   // 128
    // ---- 2) z = xn @ W_in + b_in  (bf16 only) ----
    gemm_bf16<1, 0, 0, 0, 0, 1, 1><<<Mt * 8, 256, 0, stream>>>(
        xn_bf, W_inT, b_in, nullptr, nullptr, nullptr,
        nullptr, z_bf, Mt, 8, D_MODEL);

    // ---- 3) s3 = z @ [W_xs|W_B|W_C] + bias3  (f32) ----
    gemm_bf16<1, 0, 0, 0, 1, 0, 0><<<Mt * 3, 256, 0, stream>>>(
        z_bf, W3T, bias3, nullptr, nullptr, nullptr,
        s3, nullptr, Mt, 3, D_MODEL);

    // ---- 4) chunked scan (fp32 exact), fused *C_sel -> ys_bf ----
    scan_p1<<<dim3(NCHUNK, BATCH), 128, 0, stream>>>(s3, A_log, hbuf, Ebuf);
    scan_p2<<<1, 512, 0, stream>>>(A_log, Ebuf, Gbuf);
    scan_p3<<<dim3(NCHUNK, BATCH), 128, 0, stream>>>(s3, A_log, hbuf, Gbuf, ys_bf);

    // ---- 5) y1 = ys @ W_so + D*z  (bf16 out, bf16 addmat) ----
    gemm_bf16<0, 1, 1, 1, 0, 1, 1><<<Mt * 8, 256, 0, stream>>>(
        ys_bf, W_soT, nullptr, nullptr, z_bf, Dvec,
        nullptr, y1_bf, Mt, 8, D_STATE);

    // ---- 6) out = y1 @ W_out + b_out + x (f32 residual) ----
    gemm_bf16<1, 1, 0, 0, 1, 0, 1><<<Mt * 8, 256, 0, stream>>>(
        y1_bf, W_outT, b_out, x, nullptr, nullptr,
        out, nullptr, Mt, 8, D_MODEL);
}

// Round 4
// 284.163 us; speedup vs baseline: 4.6932x; 1.1893x over previous
//
#include <hip/hip_runtime.h>
#include <math.h>

#define D_MODEL 1024
#define D_STATE 128
#define SEQ_LEN 4096
#define BATCH 4
#define NTOK (BATCH * SEQ_LEN)      // 16384
#define LN_EPS 1e-3f
#define NCHUNK 128
#define LCHUNK (SEQ_LEN / NCHUNK)   // 32

typedef __attribute__((ext_vector_type(8))) short bf16x8;
typedef __attribute__((ext_vector_type(4))) float f32x4;

__device__ __forceinline__ short f2bf(float f) {
    union { float f; unsigned u; } v; v.f = f;
    unsigned r = v.u + 0x7FFFu + ((v.u >> 16) & 1u);   // RNE
    return (short)(r >> 16);
}
__device__ __forceinline__ float bf2f(short s) {
    union { unsigned u; float f; } v; v.u = ((unsigned)(unsigned short)s) << 16;
    return v.f;
}

// ---------------- LayerNorm -> bf16 output ----------------
__global__ __launch_bounds__(256) void ln_kernel(const float* __restrict__ x,
                                                 const float* __restrict__ gamma,
                                                 const float* __restrict__ beta,
                                                 short* __restrict__ xn_bf) {
    int row = blockIdx.x;
    const float4* xr = (const float4*)(x + (size_t)row * D_MODEL);
    float4 v = xr[threadIdx.x];
    float s1 = v.x + v.y + v.z + v.w;
    float s2 = v.x * v.x + v.y * v.y + v.z * v.z + v.w * v.w;
    for (int off = 32; off; off >>= 1) {
        s1 += __shfl_down(s1, off);
        s2 += __shfl_down(s2, off);
    }
    __shared__ float ls1[4], ls2[4];
    int wid = threadIdx.x >> 6, lane = threadIdx.x & 63;
    if (lane == 0) { ls1[wid] = s1; ls2[wid] = s2; }
    __syncthreads();
    s1 = ls1[0] + ls1[1] + ls1[2] + ls1[3];
    s2 = ls2[0] + ls2[1] + ls2[2] + ls2[3];
    float mu = s1 * (1.0f / D_MODEL);
    float var = s2 * (1.0f / D_MODEL) - mu * mu;
    float r = rsqrtf(var + LN_EPS);
    float4 g = ((const float4*)gamma)[threadIdx.x];
    float4 b = ((const float4*)beta)[threadIdx.x];
    short4 o;
    o.x = f2bf((v.x - mu) * r * g.x + b.x);
    o.y = f2bf((v.y - mu) * r * g.y + b.y);
    o.z = f2bf((v.z - mu) * r * g.z + b.z);
    o.w = f2bf((v.w - mu) * r * g.w + b.w);
    ((short4*)(xn_bf + (size_t)row * D_MODEL))[threadIdx.x] = o;
}

// ---------------- fused weight prep: all transposes + bias3 in ONE launch ----
__global__ __launch_bounds__(256) void prep_kernel(
    const float* __restrict__ W_in, const float* __restrict__ W_xs,
    const float* __restrict__ W_B, const float* __restrict__ W_C,
    const float* __restrict__ W_so, const float* __restrict__ W_out,
    const float* __restrict__ bB, const float* __restrict__ bC,
    short* __restrict__ W_inT, short* __restrict__ W3T,
    short* __restrict__ W_soT, short* __restrict__ W_outT,
    float* __restrict__ bias3) {
    int blk = blockIdx.x;
    const float* in; short* out; int K, N, tile;
    if (blk < 1024)      { in = W_in;  out = W_inT;           K = 1024; N = 1024; tile = blk; }
    else if (blk < 1152) { in = W_xs;  out = W3T;             K = 1024; N = 128;  tile = blk - 1024; }
    else if (blk < 1280) { in = W_B;   out = W3T + 128*1024;  K = 1024; N = 128;  tile = blk - 1152; }
    else if (blk < 1408) { in = W_C;   out = W3T + 256*1024;  K = 1024; N = 128;  tile = blk - 1280; }
    else if (blk < 1536) { in = W_so;  out = W_soT;           K = 128;  N = 1024; tile = blk - 1408; }
    else if (blk < 2560) { in = W_out; out = W_outT;          K = 1024; N = 1024; tile = blk - 1536; }
    else {
        int t = threadIdx.y * 32 + threadIdx.x;
        for (int n = t; n < 384; n += 256)
            bias3[n] = (n < 128) ? 0.f : ((n < 256) ? bB[n - 128] : bC[n - 256]);
        return;
    }
    __shared__ float t32[32][33];
    int ntiles = N / 32;
    int nb = (tile % ntiles) * 32, kb = (tile / ntiles) * 32;
    int tx = threadIdx.x, ty = threadIdx.y;   // 32 x 8
#pragma unroll
    for (int i = 0; i < 4; ++i)
        t32[ty + 8 * i][tx] = in[(size_t)(kb + ty + 8 * i) * N + nb + tx];
    __syncthreads();
#pragma unroll
    for (int i = 0; i < 4; ++i)
        out[(size_t)(nb + ty + 8 * i) * K + kb + tx] = f2bf(t32[tx][ty + 8 * i]);
}

// ---------------- bf16 MFMA GEMM: BK=64, XOR-swizzled LDS, XCD swizzle ------
// C[M,N] = A[M,K](bf16) @ BT[N,K](bf16)^T, fp32 accum. 1-D grid of Mt*Nt tiles.
// LDS layout: row-major [row][8 slots of 8 bf16], slot = kc8 ^ (row&7) so the
// fragment ds_read_b128s of 16 consecutive-row lanes spread over all 32 banks.
template<int HAS_BIAS, int HAS_ADD, int ADD_BF, int HAS_SCALE, int OUT_F32, int OUT_BF, int SWZ>
__global__ __launch_bounds__(256, 4) void gemm_bf16(
    const short* __restrict__ A, const short* __restrict__ BT,
    const float* __restrict__ bias,
    const float* __restrict__ addf, const short* __restrict__ addb,
    const float* __restrict__ addscale,
    float* __restrict__ Cf, short* __restrict__ Cbf,
    int Mt, int Nt, int K) {
    __shared__ short As[128 * 64];   // 16 KiB
    __shared__ short Bs[128 * 64];   // 16 KiB
    int p = blockIdx.x;
    int mtile, ntile;
    if (SWZ) {           // xcd = p&7; each XCD runs (m, n=0..7) consecutively
        int k = p & 7, q = p >> 3;
        ntile = q & 7;
        mtile = k + 8 * (q >> 3);
    } else {
        mtile = p % Mt;
        ntile = p / Mt;
    }
    int m0 = mtile * 128, n0 = ntile * 128;
    int N = Nt * 128;
    int tid = threadIdx.x;
    int lane = tid & 63;
    int w = tid >> 6;
    int quad = lane >> 4, r16 = lane & 15;
    int wm = (w & 1) * 64, wn = (w >> 1) * 64;

    f32x4 acc[4][4] = {};

    for (int k0 = 0; k0 < K; k0 += 64) {
#pragma unroll
        for (int it = 0; it < 4; ++it) {
            int seg = it * 256 + tid;          // 0..1023
            int row = seg >> 3, slot = seg & 7;
            int kc8 = slot ^ (row & 7);
            const short* gp = A + (size_t)(m0 + row) * K + k0 + kc8 * 8;
            __builtin_amdgcn_global_load_lds(
                (const __attribute__((address_space(1))) unsigned*)gp,
                (__attribute__((address_space(3))) unsigned*)(As + seg * 8), 16, 0, 0);
        }
#pragma unroll
        for (int it = 0; it < 4; ++it) {
            int seg = it * 256 + tid;
            int row = seg >> 3, slot = seg & 7;
            int kc8 = slot ^ (row & 7);
            const short* gp = BT + (size_t)(n0 + row) * K + k0 + kc8 * 8;
            __builtin_amdgcn_global_load_lds(
                (const __attribute__((address_space(1))) unsigned*)gp,
                (__attribute__((address_space(3))) unsigned*)(Bs + seg * 8), 16, 0, 0);
        }
        __syncthreads();

        const short* abase = As + (wm + r16) * 64;
        const short* bbase = Bs + (wn + r16) * 64;
        int sw = r16 & 7;
#pragma unroll
        for (int kk = 0; kk < 2; ++kk) {
            int phys = ((quad + 4 * kk) ^ sw) * 8;
            bf16x8 af[4], bfr[4];
#pragma unroll
            for (int i = 0; i < 4; ++i) af[i] = *(const bf16x8*)(abase + i * 16 * 64 + phys);
#pragma unroll
            for (int j = 0; j < 4; ++j) bfr[j] = *(const bf16x8*)(bbase + j * 16 * 64 + phys);
#pragma unroll
            for (int i = 0; i < 4; ++i)
#pragma unroll
                for (int j = 0; j < 4; ++j)
                    acc[i][j] = __builtin_amdgcn_mfma_f32_16x16x32_bf16(af[i], bfr[j], acc[i][j], 0, 0, 0);
        }
        __syncthreads();
    }

#pragma unroll
    for (int i = 0; i < 4; ++i) {
#pragma unroll
        for (int j = 0; j < 4; ++j) {
            int col = n0 + wn + j * 16 + r16;
            float bv = HAS_BIAS ? bias[col] : 0.f;
            float sc = HAS_SCALE ? addscale[col] : 1.f;
#pragma unroll
            for (int pr = 0; pr < 4; ++pr) {
                int row = m0 + wm + i * 16 + quad * 4 + pr;
                float v = acc[i][j][pr] + bv;
                if (HAS_ADD) {
                    float av = ADD_BF ? bf2f(addb[(size_t)row * N + col])
                                      : addf[(size_t)row * N + col];
                    v += sc * av;
                }
                if (OUT_F32) Cf[(size_t)row * N + col] = v;
                if (OUT_BF) Cbf[(size_t)row * N + col] = f2bf(v);
            }
        }
    }
}

// ---------------- Chunked linear scan (exact FFT-conv replacement) ----------------
__global__ __launch_bounds__(128) void scan_p1(const float* __restrict__ s3,
                                               const float* __restrict__ A_log,
                                               float* __restrict__ hbuf,
                                               float* __restrict__ Ebuf) {
    int s = threadIdx.x;
    int c = blockIdx.x, b = blockIdx.y;
    float a = expf(-expf(A_log[s]));
    float h = 0.f;
    size_t base = (size_t)b * SEQ_LEN + (size_t)c * LCHUNK;
#pragma unroll 8
    for (int i = 0; i < LCHUNK; ++i) {
        size_t r = base + i;
        float u = s3[r * 384 + s] * s3[r * 384 + 128 + s];
        h = a * h + u;
        hbuf[r * 128 + s] = h;
    }
    Ebuf[((size_t)b * NCHUNK + c) * 128 + s] = h;
}

__global__ __launch_bounds__(512) void scan_p2(const float* __restrict__ A_log,
                                               const float* __restrict__ Ebuf,
                                               float* __restrict__ Gbuf) {
    int tid = threadIdx.x;
    int b = tid >> 7, s = tid & 127;
    float pw = expf(-expf(A_log[s]) * (float)LCHUNK);
    float G = 0.f;
    for (int c0 = 0; c0 < NCHUNK; c0 += 16) {
        float e[16];
#pragma unroll
        for (int t = 0; t < 16; ++t)
            e[t] = Ebuf[((size_t)b * NCHUNK + c0 + t) * 128 + s];
#pragma unroll
        for (int t = 0; t < 16; ++t) {
            G = pw * G + e[t];
            Gbuf[((size_t)b * NCHUNK + c0 + t) * 128 + s] = G;
        }
    }
}

__global__ __launch_bounds__(128) void scan_p3(const float* __restrict__ s3,
                                               const float* __restrict__ A_log,
                                               const float* __restrict__ hbuf,
                                               const float* __restrict__ Gbuf,
                                               short* __restrict__ ys_bf) {
    int s = threadIdx.x;
    int c = blockIdx.x, b = blockIdx.y;
    float a = expf(-expf(A_log[s]));
    float carry = (c == 0) ? 0.f : Gbuf[((size_t)b * NCHUNK + c - 1) * 128 + s];
    float p = a;
    size_t base = (size_t)b * SEQ_LEN + (size_t)c * LCHUNK;
#pragma unroll 8
    for (int i = 0; i < LCHUNK; ++i) {
        size_t r = base + i;
        float h = hbuf[r * 128 + s] + p * carry;
        p *= a;
        ys_bf[r * 128 + s] = f2bf(h * s3[r * 384 + 256 + s]);
    }
}

extern "C" void kernel_launch(void* const* d_in, const int* in_sizes, int n_in,
                              void* d_out, int out_size, void* d_ws, size_t ws_size,
                              hipStream_t stream) {
    const float* x     = (const float*)d_in[0];
    const float* ln_g  = (const float*)d_in[1];
    const float* ln_b  = (const float*)d_in[2];
    const float* W_in  = (const float*)d_in[3];
    const float* b_in  = (const float*)d_in[4];
    const float* W_xs  = (const float*)d_in[5];
    const float* W_B   = (const float*)d_in[6];
    const float* b_B   = (const float*)d_in[7];
    const float* W_C   = (const float*)d_in[8];
    const float* b_C   = (const float*)d_in[9];
    const float* A_log = (const float*)d_in[10];
    const float* Dvec  = (const float*)d_in[11];
    const float* W_so  = (const float*)d_in[12];
    const float* W_out = (const float*)d_in[13];
    const float* b_out = (const float*)d_in[14];
    float* out = (float*)d_out;

    // ---- workspace carve (bytes) ----
    char* w = (char*)d_ws;
    size_t off = 0;
    short* xn_bf = (short*)(w + off);                       // region 0: 32 MiB
    float* hbuf  = (float*)(w + off);                       //   reuses region 0 after GEMM1
    short* ys_bf = (short*)(w + off + 8388608);             //   after hbuf (8 MiB)
    off += (size_t)NTOK * D_MODEL * 2;
    short* z_bf  = (short*)(w + off);                       // region 1: 32 MiB
    off += (size_t)NTOK * D_MODEL * 2;
    short* y1_bf = (short*)(w + off);                       // region 2: 32 MiB
    off += (size_t)NTOK * D_MODEL * 2;
    float* s3    = (float*)(w + off); off += (size_t)NTOK * 384 * 4;       // 24 MiB
    float* Ebuf  = (float*)(w + off); off += (size_t)BATCH * NCHUNK * 128 * 4;
    float* Gbuf  = (float*)(w + off); off += (size_t)BATCH * NCHUNK * 128 * 4;
    short* W_inT  = (short*)(w + off); off += (size_t)D_MODEL * D_MODEL * 2;
    short* W3T    = (short*)(w + off); off += (size_t)384 * D_MODEL * 2;
    short* W_soT  = (short*)(w + off); off += (size_t)D_MODEL * D_STATE * 2;
    short* W_outT = (short*)(w + off); off += (size_t)D_MODEL * D_MODEL * 2;
    float* bias3  = (float*)(w + off); off += 2048;

    // ---- weight prep (single launch) ----
    prep_kernel<<<2561, dim3(32, 8), 0, stream>>>(W_in, W_xs, W_B, W_C, W_so, W_out,
                                                  b_B, b_C, W_inT, W3T, W_soT, W_outT, bias3);

    // ---- 1) LayerNorm -> bf16 ----
    ln_kernel<<<NTOK, 256, 0, stream>>>(x, ln_g, ln_b, xn_bf);

    const int Mt = NTOK / 128;   // 128
    // ---- 2) z = xn @ W_in + b_in  (bf16) ----
    gemm_bf16<1, 0, 0, 0, 0, 1, 1><<<Mt * 8, 256, 0, stream>>>(
        xn_bf, W_inT, b_in, nullptr, nullptr, nullptr,
        nullptr, z_bf, Mt, 8, D_MODEL);

    // ---- 3) s3 = z @ [W_xs|W_B|W_C] + bias3  (f32) ----
    gemm_bf16<1, 0, 0, 0, 1, 0, 0><<<Mt * 3, 256, 0, stream>>>(
        z_bf, W3T, bias3, nullptr, nullptr, nullptr,
        s3, nullptr, Mt, 3, D_MODEL);

    // ---- 4) chunked scan (fp32 exact), fused *C_sel -> ys_bf ----
    scan_p1<<<dim3(NCHUNK, BATCH), 128, 0, stream>>>(s3, A_log, hbuf, Ebuf);
    scan_p2<<<1, 512, 0, stream>>>(A_log, Ebuf, Gbuf);
    scan_p3<<<dim3(NCHUNK, BATCH), 128, 0, stream>>>(s3, A_log, hbuf, Gbuf, ys_bf);

    // ---- 5) y1 = ys @ W_so + D*z  (bf16 out, bf16 addmat) ----
    gemm_bf16<0, 1, 1, 1, 0, 1, 1><<<Mt * 8, 256, 0, stream>>>(
        ys_bf, W_soT, nullptr, nullptr, z_bf, Dvec,
        nullptr, y1_bf, Mt, 8, D_STATE);

    // ---- 6) out = y1 @ W_out + b_out + x (f32 residual) ----
    gemm_bf16<1, 1, 0, 0, 1, 0, 1><<<Mt * 8, 256, 0, stream>>>(
        y1_bf, W_outT, b_out, x, nullptr, nullptr,
        out, nullptr, Mt, 8, D_MODEL);
}